// Round 10
// baseline (287.573 us; speedup 1.0000x reference)
//
#include <hip/hip_runtime.h>
#include <hip/hip_bf16.h>
#include <cstdint>

typedef unsigned short u16;
typedef __bf16 bf16x8 __attribute__((ext_vector_type(8)));
typedef float f32x4 __attribute__((ext_vector_type(4)));
typedef unsigned short u16x4 __attribute__((ext_vector_type(4)));
typedef unsigned uint2v __attribute__((ext_vector_type(2)));

#define B_ 2
#define T_ 2048
#define C_ 2048
#define NH_ 16
#define NKV_ 4
#define HD_ 128
// (1/sqrt(128)) * log2(e) — folded into Q
#define K2_ 0.12752004650581538f

__device__ __forceinline__ u16 f2bf(float f) {
    unsigned u = __builtin_bit_cast(unsigned, f);
    unsigned r = u + 0x7FFFu + ((u >> 16) & 1u);
    return (u16)(r >> 16);
}

__device__ __forceinline__ unsigned cvtpk(float a, float b) {
    unsigned r;
    asm("v_cvt_pk_bf16_f32 %0, %1, %2" : "=v"(r) : "v"(a), "v"(b));
    return r;
}

__device__ __forceinline__ void gl16(const void* g, void* l) {
    auto gp = reinterpret_cast<const __attribute__((address_space(1))) unsigned*>(
        reinterpret_cast<uintptr_t>(g));
    auto lp = reinterpret_cast<__attribute__((address_space(3))) unsigned*>(
        reinterpret_cast<uintptr_t>(l));
    __builtin_amdgcn_global_load_lds(gp, lp, 16, 0, 0);
}

// ---------- transpose + fp32->bf16 convert: in [2048][N] -> out [N][2048] ----------
__global__ void transpose_conv(const float* __restrict__ in, u16* __restrict__ out, int N) {
    __shared__ float tile[32][33];
    int n0 = blockIdx.x * 32, k0 = blockIdx.y * 32;
    int tx = threadIdx.x, ty = threadIdx.y;  // 32 x 8
#pragma unroll
    for (int i = 0; i < 4; ++i)
        tile[ty * 4 + i][tx] = in[(size_t)(k0 + ty * 4 + i) * N + n0 + tx];
    __syncthreads();
#pragma unroll
    for (int i = 0; i < 4; ++i)
        out[(size_t)(n0 + ty * 4 + i) * 2048 + k0 + tx] = f2bf(tile[tx][ty * 4 + i]);
}

// ---------- fp32 -> bf16 convert (x) ----------
__global__ void convert4(const float4* __restrict__ in, u16* __restrict__ out) {
    int i = blockIdx.x * 256 + threadIdx.x;
    float4 v = in[i];
    u16x4 o;
    o[0] = f2bf(v.x); o[1] = f2bf(v.y); o[2] = f2bf(v.z); o[3] = f2bf(v.w);
    ((u16x4*)out)[i] = o;
}

// ---------- GEMM: C[M][N] f32 = A[M][K] bf16 * BT[N][K] bf16 ----------
// 2-phase dbuf, stage(next) before compute(cur), granule XOR swizzle, XCD chunking.
__global__ __launch_bounds__(256, 2) void gemm_bf16(const u16* __restrict__ A,
                                                    const u16* __restrict__ BT,
                                                    float* __restrict__ C, int N, int K) {
    __shared__ __align__(16) u16 As[2][128 * 64];
    __shared__ __align__(16) u16 Bs[2][128 * 64];
    int nwg = gridDim.x * gridDim.y;
    int bid = blockIdx.y * gridDim.x + blockIdx.x;
    int nb = (bid & 7) * (nwg >> 3) + (bid >> 3);
    int bx = nb % gridDim.x, by = nb / gridDim.x;

    int t = threadIdx.x;
    int w = t >> 6, l = t & 63;
    int wr = w >> 1, wc = w & 1;
    int lg = l >> 4, lr = l & 15;
    int m0 = by * 128, n0 = bx * 128;
    f32x4 acc[4][4] = {};

    size_t goff[4];
#pragma unroll
    for (int i = 0; i < 4; ++i) {
        int g = t + i * 256;
        goff[i] = (size_t)(g >> 3) * K * 2 + (size_t)(((g & 7) ^ ((g >> 3) & 7)) * 16);
    }
    const char* Ab = (const char*)A + (size_t)m0 * K * 2;
    const char* Bb = (const char*)BT + (size_t)n0 * K * 2;

    auto stage = [&](int kt, int buf) {
        char* Ad = (char*)As[buf] + t * 16;
        char* Bd = (char*)Bs[buf] + t * 16;
#pragma unroll
        for (int i = 0; i < 4; ++i) {
            gl16(Ab + (size_t)kt * 2 + goff[i], Ad + i * 4096);
            gl16(Bb + (size_t)kt * 2 + goff[i], Bd + i * 4096);
        }
    };

    stage(0, 0);
    int nk = K >> 6;
    for (int ki = 0; ki < nk; ++ki) {
        asm volatile("s_waitcnt vmcnt(0)" ::: "memory");
        __builtin_amdgcn_s_barrier();
        __builtin_amdgcn_sched_barrier(0);
        int cur = ki & 1;
        if (ki + 1 < nk) stage((ki + 1) * 64, cur ^ 1);
#pragma unroll
        for (int kk = 0; kk < 2; ++kk) {
            bf16x8 af[4], bfr[4];
#pragma unroll
            for (int m = 0; m < 4; ++m)
                af[m] = *(const bf16x8*)&As[cur][(wr * 64 + m * 16 + lr) * 64 +
                                                (((kk * 4 + lg) ^ (lr & 7)) * 8)];
#pragma unroll
            for (int n = 0; n < 4; ++n)
                bfr[n] = *(const bf16x8*)&Bs[cur][(wc * 64 + n * 16 + lr) * 64 +
                                                 (((kk * 4 + lg) ^ (lr & 7)) * 8)];
#pragma unroll
            for (int m = 0; m < 4; ++m)
#pragma unroll
                for (int n = 0; n < 4; ++n)
                    acc[m][n] = __builtin_amdgcn_mfma_f32_16x16x32_bf16(af[m], bfr[n], acc[m][n], 0, 0, 0);
        }
    }
#pragma unroll
    for (int m = 0; m < 4; ++m) {
        int row = m0 + wr * 64 + m * 16 + lg * 4;
#pragma unroll
        for (int n = 0; n < 4; ++n) {
            int col = n0 + wc * 64 + n * 16 + lr;
            float* Cp = C + (size_t)row * N + col;
#pragma unroll
            for (int r = 0; r < 4; ++r)
                Cp[(size_t)r * N] = acc[m][n][r];
        }
    }
}

// ---------- RoPE + RMSNorm on q and k. One wave per 128-elem head-vector ----------
__global__ void rope_rms(const float* __restrict__ qkv, const float* __restrict__ cs,
                         const float* __restrict__ sn, u16* __restrict__ qh,
                         u16* __restrict__ kh) {
    int task = blockIdx.x * 4 + (threadIdx.x >> 6);
    int l = threadIdx.x & 63;
    const float* in;
    u16* out;
    int tpos;
    float post = 1.0f;
    if (task < 65536) {               // q: 4096 rows * 16 heads
        int row = task >> 4, h = task & 15;
        in = qkv + (size_t)row * 3072 + h * 128;
        int b = row >> 11; tpos = row & 2047;
        out = qh + ((size_t)(b * NH_ + h) * T_ + tpos) * HD_;
        post = K2_;
    } else {                          // k: 4096 rows * 4 heads
        int t2 = task - 65536;
        int row = t2 >> 2, h = t2 & 3;
        in = qkv + (size_t)row * 3072 + 2048 + h * 128;
        int b = row >> 11; tpos = row & 2047;
        out = kh + ((size_t)(b * NKV_ + h) * T_ + tpos) * HD_;
    }
    float x1 = in[l], x2 = in[l + 64];
    float c = cs[tpos * 64 + l], s = sn[tpos * 64 + l];
    float o1 = x1 * c + x2 * s;
    float o2 = -x1 * s + x2 * c;
    float ss = o1 * o1 + o2 * o2;
#pragma unroll
    for (int m = 1; m < 64; m <<= 1) ss += __shfl_xor(ss, m);
    float r = rsqrtf(ss * (1.0f / 128.0f) + 1.1920929e-07f) * post;
    out[l] = f2bf(o1 * r);
    out[l + 64] = f2bf(o2 * r);
}

// ---------- V extract + transpose -> tiled V^T: vt[b*4+kvh][kv-tile(32)][128][64] bf16 ----------
__global__ void transpose_v(const float* __restrict__ qkv, u16* __restrict__ vt) {
    __shared__ float tile[32][33];
    int t0 = blockIdx.x * 32;   // 64
    int d0 = blockIdx.y * 32;   // 4
    int bk = blockIdx.z;        // 8 = b*4+kvh
    int b = bk >> 2, kvh = bk & 3;
    int tx = threadIdx.x, ty = threadIdx.y;  // 32 x 8
#pragma unroll
    for (int i = 0; i < 4; ++i)
        tile[ty * 4 + i][tx] =
            qkv[(size_t)(b * 2048 + t0 + ty * 4 + i) * 3072 + 2560 + kvh * 128 + d0 + tx];
    __syncthreads();
    int tb = t0 >> 6;            // kv-tile index (constant per block)
    int c0 = t0 & 32;            // column base within tile
#pragma unroll
    for (int i = 0; i < 4; ++i) {
        int d = d0 + ty * 4 + i;
        vt[(((size_t)bk * 32 + tb) * 128 + d) * 64 + c0 + tx] = f2bf(tile[tx][ty * 4 + i]);
    }
}

// ---------- causal GQA flash attention ----------
// 512 blocks x 2 waves (2 heads share K). Wave does strip j then 63-j: 33 iters uniform.
// K staged in LDS (dbuf, XOR swizzle); V^T tiles direct global->reg, issued BEFORE
// stageK so PV's vmcnt wait leaves the K prefetch in flight (T4). l-sum via ones-MFMA.
// LDS = 32K (K dbuf) + 4K (P) = 36864 B -> 4 blocks/CU = 8 waves/CU.
__global__ __launch_bounds__(128, 2) void attn(const u16* __restrict__ Q,
                                               const u16* __restrict__ Kk,
                                               const u16* __restrict__ Vt,
                                               u16* __restrict__ Y) {
    extern __shared__ __align__(16) u16 sm[];
    u16* Ks = sm;            // [2][64*128]
    u16* Pb = sm + 16384;    // [2][32*32], granule-XOR swizzled

    int bid = blockIdx.x;
    int xcd = bid & 7;
    int b = xcd >> 2, kvh = xcd & 3;
    int r_ = bid >> 3;                   // 0..63
    int hp = r_ & 1;                     // head pair
    int j = r_ >> 1;                     // 0..31: strips (j, 63-j)
    int NA = (j >> 1) + 1;               // iters for strip A; NB = 33-NA
    int t = threadIdx.x;
    int w = t >> 6, l = t & 63;
    int lg = l >> 4, lr = l & 15;
    int h = kvh * 4 + hp * 2 + w;
    int qwA = j * 32, qwB = (63 - j) * 32;

    const u16* Qp = Q + (size_t)(b * NH_ + h) * T_ * HD_;
    const u16* Kp = Kk + (size_t)(b * NKV_ + kvh) * T_ * HD_;
    const u16* Vb = Vt + (size_t)(b * NKV_ + kvh) * 32 * 8192;
    u16* Yp = Y + (size_t)(b * T_) * 2048 + h * HD_;
    u16* Pw = Pb + w * 1024;

    size_t koff[8];
#pragma unroll
    for (int i = 0; i < 8; ++i) {
        int g = t + i * 128;
        koff[i] = (size_t)(g >> 4) * 256 + (size_t)(((g & 15) ^ ((g >> 4) & 15)) * 16);
    }
    auto stageK = [&](int kv0, int buf) {
        const char* Kb = (const char*)Kp + (size_t)kv0 * 256;
        char* Kd = (char*)Ks + buf * 16384 + t * 16;
#pragma unroll
        for (int i = 0; i < 8; ++i) gl16(Kb + koff[i], Kd + i * 2048);
    };

    bf16x8 aq[2][4];
    auto loadQ = [&](int qw2) {
#pragma unroll
        for (int qf = 0; qf < 2; ++qf)
#pragma unroll
            for (int ch = 0; ch < 4; ++ch)
                aq[qf][ch] = *(const bf16x8*)(Qp + (size_t)(qw2 + qf * 16 + lr) * HD_ + ch * 32 + lg * 8);
    };

    bf16x8 ones;
#pragma unroll
    for (int i = 0; i < 8; ++i) ones[i] = __builtin_bit_cast(__bf16, (u16)0x3F80);

    f32x4 acc[2][8] = {};
    f32x4 accl[2] = {};
    float m2[2] = {-1e30f, -1e30f};

    auto epi = [&](int qw2) {
#pragma unroll
        for (int qf = 0; qf < 2; ++qf) {
            float inv4[4];
#pragma unroll
            for (int r = 0; r < 4; ++r) inv4[r] = 1.0f / accl[qf][r];
#pragma unroll
            for (int oc = 0; oc < 8; ++oc)
#pragma unroll
                for (int r = 0; r < 4; ++r)
                    Yp[(size_t)(qw2 + qf * 16 + 4 * lg + r) * 2048 + oc * 16 + lr] =
                        f2bf(acc[qf][oc][r] * inv4[r]);
        }
    };

    loadQ(qwA);
    int qw = qwA;
    stageK(0, 0);

    for (int gi = 0; gi < 33; ++gi) {
        asm volatile("s_waitcnt vmcnt(0)" ::: "memory");
        __builtin_amdgcn_s_barrier();
        __builtin_amdgcn_sched_barrier(0);
        int cur = gi & 1;
        int kvT = (gi < NA) ? gi : gi - NA;

        // ---- V tile direct global->reg FIRST (older than K prefetch in vmcnt order) ----
        const u16* Vtile = Vb + (size_t)kvT * 8192;
        bf16x8 vreg[16];
#pragma unroll
        for (int oc = 0; oc < 8; ++oc)
#pragma unroll
            for (int kk = 0; kk < 2; ++kk)
                vreg[oc * 2 + kk] = *(const bf16x8*)&Vtile[(oc * 16 + lr) * 64 + kk * 32 + lg * 8];
        __builtin_amdgcn_sched_barrier(0);

        // ---- K prefetch for next tile (stays in flight across PV's vmcnt wait) ----
        if (gi + 1 < 33) {
            int gn = gi + 1;
            stageK((gn < NA ? gn : gn - NA) * 64, cur ^ 1);
        }
        __builtin_amdgcn_sched_barrier(0);

        if (gi == NA) {
            epi(qwA);
#pragma unroll
            for (int qf = 0; qf < 2; ++qf) {
#pragma unroll
                for (int oc = 0; oc < 8; ++oc) acc[qf][oc] = f32x4{0.f, 0.f, 0.f, 0.f};
                accl[qf] = f32x4{0.f, 0.f, 0.f, 0.f};
                m2[qf] = -1e30f;
            }
            loadQ(qwB);
            qw = qwB;
        }
        int kv0 = kvT * 64;
        int kbase = cur * 8192;

        // ---- S^T = K Q^T (32 MFMA, K frags feed both qf) ----
        f32x4 sc[2][4] = {};
        __builtin_amdgcn_s_setprio(1);
#pragma unroll
        for (int ch = 0; ch < 4; ++ch)
#pragma unroll
            for (int kf = 0; kf < 4; ++kf) {
                bf16x8 bk = *(const bf16x8*)&Ks[kbase + (kf * 16 + lr) * 128 + (((ch * 4 + lg) ^ lr) * 8)];
                sc[0][kf] = __builtin_amdgcn_mfma_f32_16x16x32_bf16(bk, aq[0][ch], sc[0][kf], 0, 0, 0);
                sc[1][kf] = __builtin_amdgcn_mfma_f32_16x16x32_bf16(bk, aq[1][ch], sc[1][kf], 0, 0, 0);
            }
        __builtin_amdgcn_s_setprio(0);

        // ---- mask (diagonal tile only) ----
        if (kv0 + 63 > qw) {
#pragma unroll
            for (int qf = 0; qf < 2; ++qf) {
                int qrow = qw + qf * 16 + lr;
#pragma unroll
                for (int kf = 0; kf < 4; ++kf)
#pragma unroll
                    for (int r = 0; r < 4; ++r) {
                        int key = kv0 + kf * 16 + 4 * lg + r;
                        if (key > qrow) sc[qf][kf][r] = -1e38f;
                    }
            }
        }
        // ---- in-lane row max + cross-lg reduce ----
        float mx[2];
#pragma unroll
        for (int qf = 0; qf < 2; ++qf) {
            float m = sc[qf][0][0];
#pragma unroll
            for (int kf = 0; kf < 4; ++kf)
#pragma unroll
                for (int r = 0; r < 4; ++r) m = fmaxf(m, sc[qf][kf][r]);
            m = fmaxf(m, __shfl_xor(m, 16));
            m = fmaxf(m, __shfl_xor(m, 32));
            mx[qf] = m;
        }
        // ---- defer-max rescale (THR=8, log2 domain) ----
        bool upd = (mx[0] > m2[0] + 8.0f) || (mx[1] > m2[1] + 8.0f);
        if (__any(upd)) {
#pragma unroll
            for (int qf = 0; qf < 2; ++qf) {
                float mn = fmaxf(m2[qf], mx[qf]);
                float rs = exp2f(m2[qf] - mn);
                m2[qf] = mn;
                float rs4[4];
#pragma unroll
                for (int r = 0; r < 4; ++r) rs4[r] = __shfl(rs, 4 * lg + r, 16);
#pragma unroll
                for (int oc = 0; oc < 8; ++oc)
#pragma unroll
                    for (int r = 0; r < 4; ++r) acc[qf][oc][r] *= rs4[r];
#pragma unroll
                for (int r = 0; r < 4; ++r) accl[qf][r] *= rs4[r];
            }
        }
        // ---- p = 2^(s-m), two-pass P through 2KB/wave buffer ----
        bf16x8 ap[2][2];
#pragma unroll
        for (int kk = 0; kk < 2; ++kk) {
#pragma unroll
            for (int qf = 0; qf < 2; ++qf) {
#pragma unroll
                for (int kfl = 0; kfl < 2; ++kfl) {
                    int kf = kk * 2 + kfl;
                    float p0 = exp2f(sc[qf][kf][0] - m2[qf]);
                    float p1 = exp2f(sc[qf][kf][1] - m2[qf]);
                    float p2 = exp2f(sc[qf][kf][2] - m2[qf]);
                    float p3 = exp2f(sc[qf][kf][3] - m2[qf]);
                    uint2v pk;
                    pk[0] = cvtpk(p0, p1);
                    pk[1] = cvtpk(p2, p3);
                    int g = 2 * kfl + (lg >> 1);
                    *(uint2v*)&Pw[(qf * 16 + lr) * 32 + ((g ^ (lr & 3)) * 8) + (lg & 1) * 4] = pk;
                }
            }
            // read A-frags for this kk (same-wave DS ops are in-order)
#pragma unroll
            for (int qf = 0; qf < 2; ++qf)
                ap[qf][kk] = *(const bf16x8*)&Pw[(qf * 16 + lr) * 32 + ((lg ^ (lr & 3)) * 8)];
        }
        // ---- O += P V (32 MFMA) + l-sum via ones-MFMA (4 MFMA) ----
        __builtin_amdgcn_s_setprio(1);
#pragma unroll
        for (int qf = 0; qf < 2; ++qf)
#pragma unroll
            for (int kk = 0; kk < 2; ++kk)
                accl[qf] = __builtin_amdgcn_mfma_f32_16x16x32_bf16(ap[qf][kk], ones, accl[qf], 0, 0, 0);
#pragma unroll
        for (int oc = 0; oc < 8; ++oc)
#pragma unroll
            for (int kk = 0; kk < 2; ++kk) {
                acc[0][oc] = __builtin_amdgcn_mfma_f32_16x16x32_bf16(ap[0][kk], vreg[oc * 2 + kk], acc[0][oc], 0, 0, 0);
                acc[1][oc] = __builtin_amdgcn_mfma_f32_16x16x32_bf16(ap[1][kk], vreg[oc * 2 + kk], acc[1][oc], 0, 0, 0);
            }
        __builtin_amdgcn_s_setprio(0);
    }
    epi(qwB);
}

extern "C" void kernel_launch(void* const* d_in, const int* in_sizes, int n_in,
                              void* d_out, int out_size, void* d_ws, size_t ws_size,
                              hipStream_t stream) {
    const float* x    = (const float*)d_in[0];
    const float* cosT = (const float*)d_in[1];
    const float* sinT = (const float*)d_in[2];
    const float* wq   = (const float*)d_in[3];
    const float* wk   = (const float*)d_in[4];
    const float* wv   = (const float*)d_in[5];
    const float* wo   = (const float*)d_in[6];
    float* out = (float*)d_out;

    char* ws = (char*)d_ws;
    u16*   wqkvT = (u16*)(ws);                       // [3072][2048] bf16
    u16*   woT   = (u16*)(ws + 12582912);            // [2048][2048] bf16
    u16*   xb    = (u16*)(ws + 20971520);            // [4096][2048] bf16
    float* qkv   = (float*)(ws + 37748736);          // [4096][3072] f32
    u16*   qh    = (u16*)(ws + 88080384);            // [2][16][2048][128] bf16
    u16*   kh    = (u16*)(ws + 104857600);           // [2][4][2048][128] bf16
    u16*   vt    = (u16*)(ws + 109051904);           // [2][4][32][128][64] bf16 (tiled V^T)
    u16*   y     = xb;                               // reuse (xb dead after GEMM1)

    hipFuncSetAttribute(reinterpret_cast<const void*>(&attn),
                        hipFuncAttributeMaxDynamicSharedMemorySize, 36864);

    transpose_conv<<<dim3(64, 64), dim3(32, 8), 0, stream>>>(wq, wqkvT, 2048);
    transpose_conv<<<dim3(16, 64), dim3(32, 8), 0, stream>>>(wk, wqkvT + (size_t)2048 * 2048, 512);
    transpose_conv<<<dim3(16, 64), dim3(32, 8), 0, stream>>>(wv, wqkvT + (size_t)2560 * 2048, 512);
    transpose_conv<<<dim3(64, 64), dim3(32, 8), 0, stream>>>(wo, woT, 2048);
    convert4<<<8192, 256, 0, stream>>>((const float4*)x, xb);

    gemm_bf16<<<dim3(24, 32), 256, 0, stream>>>(xb, wqkvT, qkv, 3072, 2048);

    rope_rms<<<20480, 256, 0, stream>>>(qkv, cosT, sinT, qh, kh);
    transpose_v<<<dim3(64, 4, 8), dim3(32, 8), 0, stream>>>(qkv, vt);

    attn<<<512, 128, 36864, stream>>>(qh, kh, vt, y);

    gemm_bf16<<<dim3(16, 32), 256, 0, stream>>>(y, woT, out, 2048, 2048);
}

// Round 11
// 203.774 us; speedup vs baseline: 1.4112x; 1.4112x over previous
//
#include <hip/hip_runtime.h>
#include <hip/hip_bf16.h>
#include <cstdint>

typedef unsigned short u16;
typedef __bf16 bf16x8 __attribute__((ext_vector_type(8)));
typedef float f32x4 __attribute__((ext_vector_type(4)));
typedef unsigned short u16x4 __attribute__((ext_vector_type(4)));
typedef unsigned uint2v __attribute__((ext_vector_type(2)));

#define B_ 2
#define T_ 2048
#define C_ 2048
#define NH_ 16
#define NKV_ 4
#define HD_ 128
// (1/sqrt(128)) * log2(e) — folded into Q
#define K2_ 0.12752004650581538f

__device__ __forceinline__ u16 f2bf(float f) {
    unsigned u = __builtin_bit_cast(unsigned, f);
    unsigned r = u + 0x7FFFu + ((u >> 16) & 1u);
    return (u16)(r >> 16);
}

__device__ __forceinline__ float bf2f(u16 v) {
    unsigned u = ((unsigned)v) << 16;
    return __builtin_bit_cast(float, u);
}

__device__ __forceinline__ unsigned cvtpk(float a, float b) {
    unsigned r;
    asm("v_cvt_pk_bf16_f32 %0, %1, %2" : "=v"(r) : "v"(a), "v"(b));
    return r;
}

__device__ __forceinline__ void gl16(const void* g, void* l) {
    auto gp = reinterpret_cast<const __attribute__((address_space(1))) unsigned*>(
        reinterpret_cast<uintptr_t>(g));
    auto lp = reinterpret_cast<__attribute__((address_space(3))) unsigned*>(
        reinterpret_cast<uintptr_t>(l));
    __builtin_amdgcn_global_load_lds(gp, lp, 16, 0, 0);
}

// ---------- transpose + fp32->bf16 convert: in [2048][N] -> out [N][2048] ----------
__global__ void transpose_conv(const float* __restrict__ in, u16* __restrict__ out, int N) {
    __shared__ float tile[32][33];
    int n0 = blockIdx.x * 32, k0 = blockIdx.y * 32;
    int tx = threadIdx.x, ty = threadIdx.y;  // 32 x 8
#pragma unroll
    for (int i = 0; i < 4; ++i)
        tile[ty * 4 + i][tx] = in[(size_t)(k0 + ty * 4 + i) * N + n0 + tx];
    __syncthreads();
#pragma unroll
    for (int i = 0; i < 4; ++i)
        out[(size_t)(n0 + ty * 4 + i) * 2048 + k0 + tx] = f2bf(tile[tx][ty * 4 + i]);
}

// ---------- fp32 -> bf16 convert (x) ----------
__global__ void convert4(const float4* __restrict__ in, u16* __restrict__ out) {
    int i = blockIdx.x * 256 + threadIdx.x;
    float4 v = in[i];
    u16x4 o;
    o[0] = f2bf(v.x); o[1] = f2bf(v.y); o[2] = f2bf(v.z); o[3] = f2bf(v.w);
    ((u16x4*)out)[i] = o;
}

// ---------- GEMM (f32 out): C[M][N] = A[M][K] bf16 * BT[N][K] bf16 ----------
// 2-phase dbuf, stage(next) before compute(cur), granule XOR swizzle, XCD chunking.
__global__ __launch_bounds__(256, 2) void gemm_bf16(const u16* __restrict__ A,
                                                    const u16* __restrict__ BT,
                                                    float* __restrict__ C, int N, int K) {
    __shared__ __align__(16) u16 As[2][128 * 64];
    __shared__ __align__(16) u16 Bs[2][128 * 64];
    int nwg = gridDim.x * gridDim.y;
    int bid = blockIdx.y * gridDim.x + blockIdx.x;
    int nb = (bid & 7) * (nwg >> 3) + (bid >> 3);
    int bx = nb % gridDim.x, by = nb / gridDim.x;

    int t = threadIdx.x;
    int w = t >> 6, l = t & 63;
    int wr = w >> 1, wc = w & 1;
    int lg = l >> 4, lr = l & 15;
    int m0 = by * 128, n0 = bx * 128;
    f32x4 acc[4][4] = {};

    size_t goff[4];
#pragma unroll
    for (int i = 0; i < 4; ++i) {
        int g = t + i * 256;
        goff[i] = (size_t)(g >> 3) * K * 2 + (size_t)(((g & 7) ^ ((g >> 3) & 7)) * 16);
    }
    const char* Ab = (const char*)A + (size_t)m0 * K * 2;
    const char* Bb = (const char*)BT + (size_t)n0 * K * 2;

    auto stage = [&](int kt, int buf) {
        char* Ad = (char*)As[buf] + t * 16;
        char* Bd = (char*)Bs[buf] + t * 16;
#pragma unroll
        for (int i = 0; i < 4; ++i) {
            gl16(Ab + (size_t)kt * 2 + goff[i], Ad + i * 4096);
            gl16(Bb + (size_t)kt * 2 + goff[i], Bd + i * 4096);
        }
    };

    stage(0, 0);
    int nk = K >> 6;
    for (int ki = 0; ki < nk; ++ki) {
        asm volatile("s_waitcnt vmcnt(0)" ::: "memory");
        __builtin_amdgcn_s_barrier();
        __builtin_amdgcn_sched_barrier(0);
        int cur = ki & 1;
        if (ki + 1 < nk) stage((ki + 1) * 64, cur ^ 1);
#pragma unroll
        for (int kk = 0; kk < 2; ++kk) {
            bf16x8 af[4], bfr[4];
#pragma unroll
            for (int m = 0; m < 4; ++m)
                af[m] = *(const bf16x8*)&As[cur][(wr * 64 + m * 16 + lr) * 64 +
                                                (((kk * 4 + lg) ^ (lr & 7)) * 8)];
#pragma unroll
            for (int n = 0; n < 4; ++n)
                bfr[n] = *(const bf16x8*)&Bs[cur][(wc * 64 + n * 16 + lr) * 64 +
                                                 (((kk * 4 + lg) ^ (lr & 7)) * 8)];
#pragma unroll
            for (int m = 0; m < 4; ++m)
#pragma unroll
                for (int n = 0; n < 4; ++n)
                    acc[m][n] = __builtin_amdgcn_mfma_f32_16x16x32_bf16(af[m], bfr[n], acc[m][n], 0, 0, 0);
        }
    }
#pragma unroll
    for (int m = 0; m < 4; ++m) {
        int row = m0 + wr * 64 + m * 16 + lg * 4;
#pragma unroll
        for (int n = 0; n < 4; ++n) {
            int col = n0 + wc * 64 + n * 16 + lr;
            float* Cp = C + (size_t)row * N + col;
#pragma unroll
            for (int r = 0; r < 4; ++r)
                Cp[(size_t)r * N] = acc[m][n][r];
        }
    }
}

// ---------- GEMM (bf16 out): same structure, C stored as bf16 ----------
__global__ __launch_bounds__(256, 2) void gemm_bf16o(const u16* __restrict__ A,
                                                     const u16* __restrict__ BT,
                                                     u16* __restrict__ C, int N, int K) {
    __shared__ __align__(16) u16 As[2][128 * 64];
    __shared__ __align__(16) u16 Bs[2][128 * 64];
    int nwg = gridDim.x * gridDim.y;
    int bid = blockIdx.y * gridDim.x + blockIdx.x;
    int nb = (bid & 7) * (nwg >> 3) + (bid >> 3);
    int bx = nb % gridDim.x, by = nb / gridDim.x;

    int t = threadIdx.x;
    int w = t >> 6, l = t & 63;
    int wr = w >> 1, wc = w & 1;
    int lg = l >> 4, lr = l & 15;
    int m0 = by * 128, n0 = bx * 128;
    f32x4 acc[4][4] = {};

    size_t goff[4];
#pragma unroll
    for (int i = 0; i < 4; ++i) {
        int g = t + i * 256;
        goff[i] = (size_t)(g >> 3) * K * 2 + (size_t)(((g & 7) ^ ((g >> 3) & 7)) * 16);
    }
    const char* Ab = (const char*)A + (size_t)m0 * K * 2;
    const char* Bb = (const char*)BT + (size_t)n0 * K * 2;

    auto stage = [&](int kt, int buf) {
        char* Ad = (char*)As[buf] + t * 16;
        char* Bd = (char*)Bs[buf] + t * 16;
#pragma unroll
        for (int i = 0; i < 4; ++i) {
            gl16(Ab + (size_t)kt * 2 + goff[i], Ad + i * 4096);
            gl16(Bb + (size_t)kt * 2 + goff[i], Bd + i * 4096);
        }
    };

    stage(0, 0);
    int nk = K >> 6;
    for (int ki = 0; ki < nk; ++ki) {
        asm volatile("s_waitcnt vmcnt(0)" ::: "memory");
        __builtin_amdgcn_s_barrier();
        __builtin_amdgcn_sched_barrier(0);
        int cur = ki & 1;
        if (ki + 1 < nk) stage((ki + 1) * 64, cur ^ 1);
#pragma unroll
        for (int kk = 0; kk < 2; ++kk) {
            bf16x8 af[4], bfr[4];
#pragma unroll
            for (int m = 0; m < 4; ++m)
                af[m] = *(const bf16x8*)&As[cur][(wr * 64 + m * 16 + lr) * 64 +
                                                (((kk * 4 + lg) ^ (lr & 7)) * 8)];
#pragma unroll
            for (int n = 0; n < 4; ++n)
                bfr[n] = *(const bf16x8*)&Bs[cur][(wc * 64 + n * 16 + lr) * 64 +
                                                 (((kk * 4 + lg) ^ (lr & 7)) * 8)];
#pragma unroll
            for (int m = 0; m < 4; ++m)
#pragma unroll
                for (int n = 0; n < 4; ++n)
                    acc[m][n] = __builtin_amdgcn_mfma_f32_16x16x32_bf16(af[m], bfr[n], acc[m][n], 0, 0, 0);
        }
    }
#pragma unroll
    for (int m = 0; m < 4; ++m) {
        int row = m0 + wr * 64 + m * 16 + lg * 4;
#pragma unroll
        for (int n = 0; n < 4; ++n) {
            int col = n0 + wc * 64 + n * 16 + lr;
            u16* Cp = C + (size_t)row * N + col;
#pragma unroll
            for (int r = 0; r < 4; ++r)
                Cp[(size_t)r * N] = f2bf(acc[m][n][r]);
        }
    }
}

// ---------- RoPE + RMSNorm on q and k (bf16 qkv in). One wave per head-vector ----------
__global__ void rope_rms(const u16* __restrict__ qkv, const float* __restrict__ cs,
                         const float* __restrict__ sn, u16* __restrict__ qh,
                         u16* __restrict__ kh) {
    int task = blockIdx.x * 4 + (threadIdx.x >> 6);
    int l = threadIdx.x & 63;
    const u16* in;
    u16* out;
    int tpos;
    float post = 1.0f;
    if (task < 65536) {               // q: 4096 rows * 16 heads
        int row = task >> 4, h = task & 15;
        in = qkv + (size_t)row * 3072 + h * 128;
        int b = row >> 11; tpos = row & 2047;
        out = qh + ((size_t)(b * NH_ + h) * T_ + tpos) * HD_;
        post = K2_;
    } else {                          // k: 4096 rows * 4 heads
        int t2 = task - 65536;
        int row = t2 >> 2, h = t2 & 3;
        in = qkv + (size_t)row * 3072 + 2048 + h * 128;
        int b = row >> 11; tpos = row & 2047;
        out = kh + ((size_t)(b * NKV_ + h) * T_ + tpos) * HD_;
    }
    float x1 = bf2f(in[l]), x2 = bf2f(in[l + 64]);
    float c = cs[tpos * 64 + l], s = sn[tpos * 64 + l];
    float o1 = x1 * c + x2 * s;
    float o2 = -x1 * s + x2 * c;
    float ss = o1 * o1 + o2 * o2;
#pragma unroll
    for (int m = 1; m < 64; m <<= 1) ss += __shfl_xor(ss, m);
    float r = rsqrtf(ss * (1.0f / 128.0f) + 1.1920929e-07f) * post;
    out[l] = f2bf(o1 * r);
    out[l + 64] = f2bf(o2 * r);
}

// ---------- V extract + transpose (bf16 in): qkv -> vt [B*NKV][128][2048] bf16 ----------
__global__ void transpose_v(const u16* __restrict__ qkv, u16* __restrict__ vt) {
    __shared__ u16 tile[32][34];
    int t0 = blockIdx.x * 32;   // 64
    int d0 = blockIdx.y * 32;   // 4
    int bk = blockIdx.z;        // 8 = b*4+kvh
    int b = bk >> 2, kvh = bk & 3;
    int tx = threadIdx.x, ty = threadIdx.y;  // 32 x 8
#pragma unroll
    for (int i = 0; i < 4; ++i)
        tile[ty * 4 + i][tx] =
            qkv[(size_t)(b * 2048 + t0 + ty * 4 + i) * 3072 + 2560 + kvh * 128 + d0 + tx];
    __syncthreads();
#pragma unroll
    for (int i = 0; i < 4; ++i)
        vt[((size_t)bk * 128 + d0 + ty * 4 + i) * 2048 + t0 + tx] = tile[tx][ty * 4 + i];
}

// ---------- causal GQA flash attention (round-8 best): 32-row waves, swapped-S^T ----------
// 512 blocks x 4 waves (4 heads x one 32-row strip). Lane owns 2 q-rows (qf*16+lr).
// LDS: K dbuf 32K + V dbuf 32K + P 8K = 73728 B -> 2 blocks/CU.
__global__ __launch_bounds__(256, 2) void attn(const u16* __restrict__ Q,
                                               const u16* __restrict__ Kk,
                                               const u16* __restrict__ V,
                                               u16* __restrict__ Y) {
    extern __shared__ __align__(16) u16 sm[];
    u16* Ks = sm;            // [2][64*128]
    u16* Vs = sm + 16384;    // [2][128*64]
    u16* Pb = sm + 32768;    // [4][32*32], granule-XOR swizzled

    int bid = blockIdx.x;
    int xcd = bid & 7;
    int b = xcd >> 2, kvh = xcd & 3;
    int q = bid >> 3;                           // 0..63
    int j = (q < 32) ? (63 - q) : (q - 32);     // complementary pairing
    int NN = (j >> 1) + 1;                      // kv-iterations for this strip
    int t = threadIdx.x;
    int w = t >> 6, l = t & 63;
    int lg = l >> 4, lr = l & 15;
    int h = kvh * 4 + w;
    int qw = j * 32;

    const u16* Qp = Q + (size_t)(b * NH_ + h) * T_ * HD_;
    const u16* Kp = Kk + (size_t)(b * NKV_ + kvh) * T_ * HD_;
    const u16* Vp = V + (size_t)(b * NKV_ + kvh) * HD_ * T_;
    u16* Yp = Y + (size_t)(b * T_) * 2048 + h * HD_;
    u16* Pw = Pb + w * 1024;

    size_t koff[4], voff[4];
#pragma unroll
    for (int i = 0; i < 4; ++i) {
        int g = t + i * 256;
        koff[i] = (size_t)(g >> 4) * 256 + (size_t)(((g & 15) ^ ((g >> 4) & 15)) * 16);
        voff[i] = (size_t)(g >> 3) * (T_ * 2) + (size_t)(((g & 7) ^ ((g >> 3) & 7)) * 16);
    }
    auto stage = [&](int kv0, int buf) {
        const char* Kb = (const char*)Kp + (size_t)kv0 * 256;
        const char* Vb = (const char*)Vp + (size_t)kv0 * 2;
        char* Kd = (char*)Ks + buf * 16384 + t * 16;
        char* Vd = (char*)Vs + buf * 16384 + t * 16;
#pragma unroll
        for (int i = 0; i < 4; ++i) {
            gl16(Kb + koff[i], Kd + i * 4096);
            gl16(Vb + voff[i], Vd + i * 4096);
        }
    };

    bf16x8 aq[2][4];
#pragma unroll
    for (int qf = 0; qf < 2; ++qf)
#pragma unroll
        for (int ch = 0; ch < 4; ++ch)
            aq[qf][ch] = *(const bf16x8*)(Qp + (size_t)(qw + qf * 16 + lr) * HD_ + ch * 32 + lg * 8);

    f32x4 acc[2][8] = {};
    float m2[2] = {-1e30f, -1e30f};
    float lp_[2] = {0.0f, 0.0f};

    stage(0, 0);

    for (int gi = 0; gi < NN; ++gi) {
        asm volatile("s_waitcnt vmcnt(0)" ::: "memory");
        __builtin_amdgcn_s_barrier();
        __builtin_amdgcn_sched_barrier(0);
        int cur = gi & 1;
        if (gi + 1 < NN) stage((gi + 1) * 64, cur ^ 1);
        int kv0 = gi * 64;
        int kbase = cur * 8192;

        // ---- S^T = K Q^T (32 MFMA, K frags feed both qf) ----
        f32x4 sc[2][4] = {};
        __builtin_amdgcn_s_setprio(1);
#pragma unroll
        for (int ch = 0; ch < 4; ++ch)
#pragma unroll
            for (int kf = 0; kf < 4; ++kf) {
                bf16x8 bk = *(const bf16x8*)&Ks[kbase + (kf * 16 + lr) * 128 + (((ch * 4 + lg) ^ lr) * 8)];
                sc[0][kf] = __builtin_amdgcn_mfma_f32_16x16x32_bf16(bk, aq[0][ch], sc[0][kf], 0, 0, 0);
                sc[1][kf] = __builtin_amdgcn_mfma_f32_16x16x32_bf16(bk, aq[1][ch], sc[1][kf], 0, 0, 0);
            }
        __builtin_amdgcn_s_setprio(0);

        // ---- mask (diagonal tile only) ----
        if (kv0 + 63 > qw) {
#pragma unroll
            for (int qf = 0; qf < 2; ++qf) {
                int qrow = qw + qf * 16 + lr;
#pragma unroll
                for (int kf = 0; kf < 4; ++kf)
#pragma unroll
                    for (int r = 0; r < 4; ++r) {
                        int key = kv0 + kf * 16 + 4 * lg + r;
                        if (key > qrow) sc[qf][kf][r] = -1e38f;
                    }
            }
        }
        // ---- in-lane row max + cross-lg reduce ----
        float mx[2];
#pragma unroll
        for (int qf = 0; qf < 2; ++qf) {
            float m = sc[qf][0][0];
#pragma unroll
            for (int kf = 0; kf < 4; ++kf)
#pragma unroll
                for (int r = 0; r < 4; ++r) m = fmaxf(m, sc[qf][kf][r]);
            m = fmaxf(m, __shfl_xor(m, 16));
            m = fmaxf(m, __shfl_xor(m, 32));
            mx[qf] = m;
        }
        // ---- defer-max rescale (THR=8, log2 domain) ----
        bool upd = (mx[0] > m2[0] + 8.0f) || (mx[1] > m2[1] + 8.0f);
        if (__any(upd)) {
#pragma unroll
            for (int qf = 0; qf < 2; ++qf) {
                float mn = fmaxf(m2[qf], mx[qf]);
                float rs = exp2f(m2[qf] - mn);
                m2[qf] = mn;
                lp_[qf] *= rs;
                float rs4[4];
#pragma unroll
                for (int r = 0; r < 4; ++r) rs4[r] = __shfl(rs, 4 * lg + r, 16);
#pragma unroll
                for (int oc = 0; oc < 8; ++oc)
#pragma unroll
                    for (int r = 0; r < 4; ++r) acc[qf][oc][r] *= rs4[r];
            }
        }
        // ---- p = 2^(s-m), two-pass P through 2KB/wave buffer ----
        bf16x8 ap[2][2];
#pragma unroll
        for (int kk = 0; kk < 2; ++kk) {
#pragma unroll
            for (int qf = 0; qf < 2; ++qf) {
                float ps = 0.0f;
#pragma unroll
                for (int kfl = 0; kfl < 2; ++kfl) {
                    int kf = kk * 2 + kfl;
                    float p0 = exp2f(sc[qf][kf][0] - m2[qf]);
                    float p1 = exp2f(sc[qf][kf][1] - m2[qf]);
                    float p2 = exp2f(sc[qf][kf][2] - m2[qf]);
                    float p3 = exp2f(sc[qf][kf][3] - m2[qf]);
                    ps += (p0 + p1) + (p2 + p3);
                    uint2v pk;
                    pk[0] = cvtpk(p0, p1);
                    pk[1] = cvtpk(p2, p3);
                    int g = 2 * kfl + (lg >> 1);
                    *(uint2v*)&Pw[(qf * 16 + lr) * 32 + ((g ^ (lr & 3)) * 8) + (lg & 1) * 4] = pk;
                }
                lp_[qf] += ps;
            }
            // read A-frags for this kk (same-wave DS ops are in-order)
#pragma unroll
            for (int qf = 0; qf < 2; ++qf)
                ap[qf][kk] = *(const bf16x8*)&Pw[(qf * 16 + lr) * 32 + ((lg ^ (lr & 3)) * 8)];
        }
        // ---- O += P V (32 MFMA, V frags feed both qf) ----
        __builtin_amdgcn_s_setprio(1);
#pragma unroll
        for (int oc = 0; oc < 8; ++oc)
#pragma unroll
            for (int kk = 0; kk < 2; ++kk) {
                bf16x8 bv = *(const bf16x8*)&Vs[kbase + (oc * 16 + lr) * 64 +
                                                (((kk * 4 + lg) ^ (lr & 7)) * 8)];
                acc[0][oc] = __builtin_amdgcn_mfma_f32_16x16x32_bf16(ap[0][kk], bv, acc[0][oc], 0, 0, 0);
                acc[1][oc] = __builtin_amdgcn_mfma_f32_16x16x32_bf16(ap[1][kk], bv, acc[1][oc], 0, 0, 0);
            }
        __builtin_amdgcn_s_setprio(0);
    }
    // ---- epilogue ----
#pragma unroll
    for (int qf = 0; qf < 2; ++qf) {
        float lt = lp_[qf];
        lt += __shfl_xor(lt, 16);
        lt += __shfl_xor(lt, 32);
        float inv = 1.0f / lt;
        float inv4[4];
#pragma unroll
        for (int r = 0; r < 4; ++r) inv4[r] = __shfl(inv, 4 * lg + r, 16);
#pragma unroll
        for (int oc = 0; oc < 8; ++oc)
#pragma unroll
            for (int r = 0; r < 4; ++r)
                Yp[(size_t)(qw + qf * 16 + 4 * lg + r) * 2048 + oc * 16 + lr] =
                    f2bf(acc[qf][oc][r] * inv4[r]);
    }
}

extern "C" void kernel_launch(void* const* d_in, const int* in_sizes, int n_in,
                              void* d_out, int out_size, void* d_ws, size_t ws_size,
                              hipStream_t stream) {
    const float* x    = (const float*)d_in[0];
    const float* cosT = (const float*)d_in[1];
    const float* sinT = (const float*)d_in[2];
    const float* wq   = (const float*)d_in[3];
    const float* wk   = (const float*)d_in[4];
    const float* wv   = (const float*)d_in[5];
    const float* wo   = (const float*)d_in[6];
    float* out = (float*)d_out;

    char* ws = (char*)d_ws;
    u16*   wqkvT = (u16*)(ws);                       // [3072][2048] bf16
    u16*   woT   = (u16*)(ws + 12582912);            // [2048][2048] bf16
    u16*   xb    = (u16*)(ws + 20971520);            // [4096][2048] bf16
    u16*   qkv   = (u16*)(ws + 37748736);            // [4096][3072] bf16
    u16*   qh    = (u16*)(ws + 88080384);            // [2][16][2048][128] bf16
    u16*   kh    = (u16*)(ws + 104857600);           // [2][4][2048][128] bf16
    u16*   vt    = (u16*)(ws + 109051904);           // [2][4][128][2048] bf16 (V^T)
    u16*   y     = xb;                               // reuse (xb dead after GEMM1)

    hipFuncSetAttribute(reinterpret_cast<const void*>(&attn),
                        hipFuncAttributeMaxDynamicSharedMemorySize, 73728);

    transpose_conv<<<dim3(64, 64), dim3(32, 8), 0, stream>>>(wq, wqkvT, 2048);
    transpose_conv<<<dim3(16, 64), dim3(32, 8), 0, stream>>>(wk, wqkvT + (size_t)2048 * 2048, 512);
    transpose_conv<<<dim3(16, 64), dim3(32, 8), 0, stream>>>(wv, wqkvT + (size_t)2560 * 2048, 512);
    transpose_conv<<<dim3(64, 64), dim3(32, 8), 0, stream>>>(wo, woT, 2048);
    convert4<<<8192, 256, 0, stream>>>((const float4*)x, xb);

    gemm_bf16o<<<dim3(24, 32), 256, 0, stream>>>(xb, wqkvT, qkv, 3072, 2048);

    rope_rms<<<20480, 256, 0, stream>>>(qkv, cosT, sinT, qh, kh);
    transpose_v<<<dim3(64, 4, 8), dim3(32, 8), 0, stream>>>(qkv, vt);

    attn<<<512, 256, 73728, stream>>>(qh, kh, vt, y);

    gemm_bf16<<<dim3(16, 32), 256, 0, stream>>>(y, woT, out, 2048, 2048);
}